// Round 16
// baseline (12071.755 us; speedup 1.0000x reference)
//
#include <hip/hip_runtime.h>
#include <cstdint>
#include <cstddef>

#define N_OBJ 2048
#define NUM_CLASSES 151
#define EMBED 200
#define HID 512
#define OBJ_DIM 4096
#define POS 128
#define OBJ_IN 4424   // 4096+200+128
#define EDGE_IN 4808  // 200+4096+512
#define G4 2048       // 4*HID
#define TSTEPS 2048   // virtual rows are causally dead (outputs sliced [:2048])
#define SPIN_FUSED 12000
#define OUT_PRED 309248
#define OUT_EDGE 311296

typedef unsigned long long ull;

// ----------------------------------------------------------------------------
// utility kernels
// ----------------------------------------------------------------------------
__global__ void init_sync_kernel(unsigned* p, long n) {
  long i = blockIdx.x * (long)blockDim.x + threadIdx.x;
  long stride = (long)gridDim.x * blockDim.x;
  for (; i < n; i += stride) p[i] = 0u;
}

// objemb[r][0:200] = obj_dists_in[r] @ embed1  (compact, ld=200)
__global__ void obj_embed2_kernel(const float* __restrict__ dists,
                                  const float* __restrict__ embed1,
                                  float* __restrict__ objemb) {
  int r = blockIdx.x;
  __shared__ float drow[NUM_CLASSES];
  for (int c = threadIdx.x; c < NUM_CLASSES; c += blockDim.x)
    drow[c] = dists[(size_t)r * NUM_CLASSES + c];
  __syncthreads();
  for (int j = threadIdx.x; j < EMBED; j += blockDim.x) {
    float s = 0.f;
    for (int k = 0; k < NUM_CLASSES; ++k)
      s = fmaf(drow[k], embed1[(size_t)k * EMBED + j], s);
    objemb[(size_t)r * EMBED + j] = s;
  }
}

// posemb[r][0:128] = relu(BN(box@W1+b1)@W2+b2)  (compact, ld=128)
__global__ void pos2_kernel(const float* __restrict__ box,
                            const float* __restrict__ W1, const float* __restrict__ b1,
                            const float* __restrict__ gamma, const float* __restrict__ beta,
                            const float* __restrict__ mean, const float* __restrict__ var,
                            const float* __restrict__ W2, const float* __restrict__ b2,
                            float* __restrict__ posemb) {
  int r = blockIdx.x;
  __shared__ float h[32];
  __shared__ float bx[9];
  if (threadIdx.x < 9) bx[threadIdx.x] = box[(size_t)r * 9 + threadIdx.x];
  __syncthreads();
  if (threadIdx.x < 32) {
    float s = b1[threadIdx.x];
    for (int k = 0; k < 9; ++k) s = fmaf(bx[k], W1[k * 32 + threadIdx.x], s);
    s = (s - mean[threadIdx.x]) * (1.f / sqrtf(var[threadIdx.x] + 1e-5f)) * gamma[threadIdx.x]
        + beta[threadIdx.x];
    h[threadIdx.x] = s;
  }
  __syncthreads();
  int j = threadIdx.x;
  if (j < POS) {
    float s = b2[j];
    for (int k = 0; k < 32; ++k) s = fmaf(h[k], W2[k * POS + j], s);
    posemb[(size_t)r * POS + j] = fmaxf(s, 0.f);
  }
}

// ----------------------------------------------------------------------------
// 64x64 GEMM (R11-proven): C = A@B (+bias if !ACC, += if ACC), bounds-checked
// ----------------------------------------------------------------------------
template <int ACC>
__global__ __launch_bounds__(256)
void gemm_kernel(const float* __restrict__ A, int lda,
                 const float* __restrict__ B, int ldb,
                 const float* __restrict__ bias,
                 float* __restrict__ C, int ldc,
                 int M, int N, int K) {
  __shared__ __align__(16) float As[16][68];
  __shared__ __align__(16) float Bs[16][64];
  const int row0 = blockIdx.y * 64;
  const int col0 = blockIdx.x * 64;
  const int tid = threadIdx.x;
  const int tx = tid & 15, ty = tid >> 4;
  float acc[4][4] = {};

  for (int k0 = 0; k0 < K; k0 += 16) {
#pragma unroll
    for (int l = 0; l < 4; ++l) {
      int idx = tid + l * 256;
      int m = idx >> 4, kk = idx & 15;
      int gm = row0 + m, gk = k0 + kk;
      As[kk][m] = (gm < M && gk < K) ? A[(size_t)gm * lda + gk] : 0.f;
    }
#pragma unroll
    for (int l = 0; l < 4; ++l) {
      int idx = tid + l * 256;
      int kk = idx >> 6, n = idx & 63;
      int gk = k0 + kk, gn = col0 + n;
      Bs[kk][n] = (gk < K && gn < N) ? B[(size_t)gk * ldb + gn] : 0.f;
    }
    __syncthreads();
#pragma unroll
    for (int kk = 0; kk < 16; ++kk) {
      float4 a = *reinterpret_cast<const float4*>(&As[kk][ty * 4]);
      float4 b = *reinterpret_cast<const float4*>(&Bs[kk][tx * 4]);
      acc[0][0] = fmaf(a.x, b.x, acc[0][0]); acc[0][1] = fmaf(a.x, b.y, acc[0][1]);
      acc[0][2] = fmaf(a.x, b.z, acc[0][2]); acc[0][3] = fmaf(a.x, b.w, acc[0][3]);
      acc[1][0] = fmaf(a.y, b.x, acc[1][0]); acc[1][1] = fmaf(a.y, b.y, acc[1][1]);
      acc[1][2] = fmaf(a.y, b.z, acc[1][2]); acc[1][3] = fmaf(a.y, b.w, acc[1][3]);
      acc[2][0] = fmaf(a.z, b.x, acc[2][0]); acc[2][1] = fmaf(a.z, b.y, acc[2][1]);
      acc[2][2] = fmaf(a.z, b.z, acc[2][2]); acc[2][3] = fmaf(a.z, b.w, acc[2][3]);
      acc[3][0] = fmaf(a.w, b.x, acc[3][0]); acc[3][1] = fmaf(a.w, b.y, acc[3][1]);
      acc[3][2] = fmaf(a.w, b.z, acc[3][2]); acc[3][3] = fmaf(a.w, b.w, acc[3][3]);
    }
    __syncthreads();
  }
#pragma unroll
  for (int i = 0; i < 4; ++i) {
    int gm = row0 + ty * 4 + i;
    if (gm >= M) continue;
#pragma unroll
    for (int j = 0; j < 4; ++j) {
      int gn = col0 + tx * 4 + j;
      if (gn >= N) continue;
      size_t o = (size_t)gm * ldc + gn;
      if (ACC) C[o] += acc[i][j];
      else C[o] = acc[i][j] + (bias ? bias[gn] : 0.f);
    }
  }
}

// ----------------------------------------------------------------------------
// 64x128 GEMM, 4x8/thread: 2x FMA per LDS read vs gemm64 with the SAME proven
// conflict-free patterns (As broadcast via ty*4; Bs 2-way-free via tx*4 and
// tx*4+64 — NOT the R13-failed ty*8). For the big K=4096 GEMMs.
// ----------------------------------------------------------------------------
template <int ACC>
__global__ __launch_bounds__(256)
void gemm48_kernel(const float* __restrict__ A, int lda,
                   const float* __restrict__ B, int ldb,
                   const float* __restrict__ bias,
                   float* __restrict__ C, int ldc,
                   int M, int N, int K) {
  __shared__ __align__(16) float As[16][68];
  __shared__ __align__(16) float Bs[16][128];
  const int row0 = blockIdx.y * 64;
  const int col0 = blockIdx.x * 128;
  const int tid = threadIdx.x;
  const int tx = tid & 15, ty = tid >> 4;
  float acc[4][8] = {};

  for (int k0 = 0; k0 < K; k0 += 16) {
#pragma unroll
    for (int l = 0; l < 4; ++l) {
      int idx = tid + l * 256;
      int m = idx >> 4, kk = idx & 15;
      int gm = row0 + m, gk = k0 + kk;
      As[kk][m] = (gm < M && gk < K) ? A[(size_t)gm * lda + gk] : 0.f;
    }
#pragma unroll
    for (int l = 0; l < 8; ++l) {
      int idx = tid + l * 256;
      int kk = idx >> 7, n = idx & 127;
      int gk = k0 + kk, gn = col0 + n;
      Bs[kk][n] = (gk < K && gn < N) ? B[(size_t)gk * ldb + gn] : 0.f;
    }
    __syncthreads();
#pragma unroll
    for (int kk = 0; kk < 16; ++kk) {
      float4 a = *reinterpret_cast<const float4*>(&As[kk][ty * 4]);
      float4 b0 = *reinterpret_cast<const float4*>(&Bs[kk][tx * 4]);
      float4 b1 = *reinterpret_cast<const float4*>(&Bs[kk][64 + tx * 4]);
      acc[0][0] = fmaf(a.x, b0.x, acc[0][0]); acc[0][1] = fmaf(a.x, b0.y, acc[0][1]);
      acc[0][2] = fmaf(a.x, b0.z, acc[0][2]); acc[0][3] = fmaf(a.x, b0.w, acc[0][3]);
      acc[0][4] = fmaf(a.x, b1.x, acc[0][4]); acc[0][5] = fmaf(a.x, b1.y, acc[0][5]);
      acc[0][6] = fmaf(a.x, b1.z, acc[0][6]); acc[0][7] = fmaf(a.x, b1.w, acc[0][7]);
      acc[1][0] = fmaf(a.y, b0.x, acc[1][0]); acc[1][1] = fmaf(a.y, b0.y, acc[1][1]);
      acc[1][2] = fmaf(a.y, b0.z, acc[1][2]); acc[1][3] = fmaf(a.y, b0.w, acc[1][3]);
      acc[1][4] = fmaf(a.y, b1.x, acc[1][4]); acc[1][5] = fmaf(a.y, b1.y, acc[1][5]);
      acc[1][6] = fmaf(a.y, b1.z, acc[1][6]); acc[1][7] = fmaf(a.y, b1.w, acc[1][7]);
      acc[2][0] = fmaf(a.z, b0.x, acc[2][0]); acc[2][1] = fmaf(a.z, b0.y, acc[2][1]);
      acc[2][2] = fmaf(a.z, b0.z, acc[2][2]); acc[2][3] = fmaf(a.z, b0.w, acc[2][3]);
      acc[2][4] = fmaf(a.z, b1.x, acc[2][4]); acc[2][5] = fmaf(a.z, b1.y, acc[2][5]);
      acc[2][6] = fmaf(a.z, b1.z, acc[2][6]); acc[2][7] = fmaf(a.z, b1.w, acc[2][7]);
      acc[3][0] = fmaf(a.w, b0.x, acc[3][0]); acc[3][1] = fmaf(a.w, b0.y, acc[3][1]);
      acc[3][2] = fmaf(a.w, b0.z, acc[3][2]); acc[3][3] = fmaf(a.w, b0.w, acc[3][3]);
      acc[3][4] = fmaf(a.w, b1.x, acc[3][4]); acc[3][5] = fmaf(a.w, b1.y, acc[3][5]);
      acc[3][6] = fmaf(a.w, b1.z, acc[3][6]); acc[3][7] = fmaf(a.w, b1.w, acc[3][7]);
    }
    __syncthreads();
  }
#pragma unroll
  for (int i = 0; i < 4; ++i) {
    int gm = row0 + ty * 4 + i;
    if (gm >= M) continue;
#pragma unroll
    for (int j = 0; j < 8; ++j) {
      int gn = col0 + ((j < 4) ? (tx * 4 + j) : (64 + tx * 4 + j - 4));
      if (gn >= N) continue;
      size_t o = (size_t)gm * ldc + gn;
      if (ACC) C[o] += acc[i][j];
      else C[o] = acc[i][j] + (bias ? bias[gn] : 0.f);
    }
  }
}

// ----------------------------------------------------------------------------
// MEGA-FUSED pipeline (R15-proven structure): obj scan -> dec scan -> argmax
// -> edge scan, one dispatch, 176 blocks. Exchange: full-array tagged pairs
// {tag=s+1, payload}, relaxed/agent atomics, zero-init per launch.
// R16 change: SPLIT POLLS — wait on own-h first (minimal width), then enc,
// then pred. Steady-state poll traffic ~3x lower; same dependency semantics,
// same bounded spins + sticky dead-latch.
// ----------------------------------------------------------------------------
__device__ __forceinline__ void rec8_body(
    int blk, const float* __restrict__ pre, const float* __restrict__ Wh,
    const float* __restrict__ Wi2, ull* hXown, const ull* encXc,
    const ull* predX, const float* __restrict__ embT, float* outEdge,
    float4 (*w4)[32][64], float* hl, int* shPred) {
  const int tid = threadIdx.x;
  const int wv = tid >> 6;
  const int l = tid & 63;
  const int o = l & 7;          // k-octant (128 k each; o<4 = own-h, o>=4 = enc)
  const int c = l >> 3;         // col-in-wave 0..7
  const int gq = c & 3;         // gate
  const int dl = c >> 2;        // dim-in-wave 0..1
  const int dim = blk * 8 + 2 * wv + dl;
  const int colw = gq * HID + dim;
  {
    const float* srcW = (o < 4) ? (Wh + (size_t)(o * 128) * G4 + colw)
                                : (Wi2 + (size_t)((o - 4) * 128) * G4 + colw);
#pragma unroll 4
    for (int j4 = 0; j4 < 32; ++j4) {
      float4 t;
      t.x = srcW[(size_t)(4 * j4 + 0) * G4];
      t.y = srcW[(size_t)(4 * j4 + 1) * G4];
      t.z = srcW[(size_t)(4 * j4 + 2) * G4];
      t.w = srcW[(size_t)(4 * j4 + 3) * G4];
      w4[wv][j4][l] = t;
    }
  }
  for (int i = tid; i < 1056; i += 256) hl[i] = 0.f;
  __syncthreads();

  float creg = 0.f;
  bool dead = false;
  for (int s = 0; s < TSTEPS; ++s) {
    float pre_v = pre[(size_t)s * G4 + colw];
    if (wv == 0) {
      const ull* srcE = encXc + (size_t)s * HID + l * 8;
      const ull* srcH = hXown + (size_t)(s - 1) * HID + l * 8;  // deref iff s>0
      ull pe[8], ph[8], pp = 0;
      // phase 1: own h (the recurrence gate) — minimal-width poll
      if (!dead && s > 0) {
        int tries = 0;
        for (;;) {
          unsigned tH = 0xFFFFFFFFu;
#pragma unroll
          for (int j = 0; j < 8; ++j) {
            ph[j] = __hip_atomic_load(srcH + j, __ATOMIC_RELAXED, __HIP_MEMORY_SCOPE_AGENT);
            tH = min(tH, (unsigned)(ph[j] >> 32));
          }
          if (__all((int)(tH >= (unsigned)s))) break;
          if (++tries > SPIN_FUSED) { dead = true; break; }
          __builtin_amdgcn_s_sleep(2);
        }
      }
      // phase 2: enc[s] (pipelined ahead; usually already valid)
      if (!dead) {
        int tries = 0;
        for (;;) {
          unsigned tE = 0xFFFFFFFFu;
#pragma unroll
          for (int j = 0; j < 8; ++j) {
            pe[j] = __hip_atomic_load(srcE + j, __ATOMIC_RELAXED, __HIP_MEMORY_SCOPE_AGENT);
            tE = min(tE, (unsigned)(pe[j] >> 32));
          }
          if (__all((int)(tE >= (unsigned)(s + 1)))) break;
          if (++tries > SPIN_FUSED) { dead = true; break; }
          __builtin_amdgcn_s_sleep(2);
        }
      }
      // phase 3: pred[s] (edge only)
      if (!dead && predX) {
        int tries = 0;
        for (;;) {
          pp = __hip_atomic_load(predX + s, __ATOMIC_RELAXED, __HIP_MEMORY_SCOPE_AGENT);
          if (__all((int)((unsigned)(pp >> 32) >= (unsigned)(s + 1)))) break;
          if (++tries > SPIN_FUSED) { dead = true; break; }
          __builtin_amdgcn_s_sleep(2);
        }
      }
      if (dead) {
#pragma unroll
        for (int j = 0; j < 8; ++j) { pe[j] = 0ull; ph[j] = 0ull; }
        pp = 0;
      }
      const int ppH = 8 * l + 4 * (l >> 4);
      const int ppE = 528 + ppH;
      if (s > 0) {
#pragma unroll
        for (int j = 0; j < 8; ++j) hl[ppH + j] = __uint_as_float((unsigned)ph[j]);
      }
#pragma unroll
      for (int j = 0; j < 8; ++j) hl[ppE + j] = __uint_as_float((unsigned)pe[j]);
      if (predX && l == 0) *shPred = (int)(unsigned)(pp & 0xFFFFFFFFull);
    }
    __syncthreads();

    float emb = 0.f;
    if (embT) emb = embT[(size_t)(*shPred) * G4 + colw];

    float a0 = 0.f, a1 = 0.f, a2 = 0.f, a3 = 0.f;
    const float* hseg = &hl[132 * o];
#pragma unroll
    for (int j4 = 0; j4 < 32; ++j4) {
      float4 w = w4[wv][j4][l];
      float4 h4 = *reinterpret_cast<const float4*>(&hseg[4 * j4]);
      a0 = fmaf(w.x, h4.x, a0); a1 = fmaf(w.y, h4.y, a1);
      a2 = fmaf(w.z, h4.z, a2); a3 = fmaf(w.w, h4.w, a3);
    }
    float acc = (a0 + a1) + (a2 + a3);
    acc += __shfl_xor(acc, 1);
    acc += __shfl_xor(acc, 2);
    acc += __shfl_xor(acc, 4);
    float full = acc + pre_v + emb;
    int gb = dl * 32;  // lanes gb, gb+8, gb+16, gb+24 hold gates i,f,g,o (R14/R15-verified)
    float vi = __shfl(full, gb), vf = __shfl(full, gb + 8);
    float vg = __shfl(full, gb + 16), vo = __shfl(full, gb + 24);
    float si = 1.f / (1.f + __expf(-vi));
    float sf = 1.f / (1.f + __expf(-vf));
    float so = 1.f / (1.f + __expf(-vo));
    creg = sf * creg + si * tanhf(vg);
    float h = so * tanhf(creg);
    if ((l & 31) == 0) {
      if (outEdge) outEdge[(size_t)s * HID + dim] = h;
      ull pvs = ((ull)(unsigned)(s + 1) << 32) | (unsigned)__float_as_uint(h);
      __hip_atomic_store(hXown + (size_t)s * HID + dim, pvs, __ATOMIC_RELAXED,
                         __HIP_MEMORY_SCOPE_AGENT);
    }
  }
}

__global__ __launch_bounds__(256, 1)
void fused_all_kernel(const float* __restrict__ preO, const float* __restrict__ objWh,
                      const float* __restrict__ preD, const float* __restrict__ decWh,
                      const float* __restrict__ decWi2,
                      const float* __restrict__ epre, const float* __restrict__ embT,
                      const float* __restrict__ edgeWh, const float* __restrict__ edgeWi2,
                      const float* __restrict__ outW, const float* __restrict__ outB,
                      ull* encX, ull* dechX, ull* edgeX, ull* predX,
                      float* out) {
  __shared__ float4 w4[4][32][64];   // 128 KB
  __shared__ float hl[1056];         // scan h staging / argmax dh+logits
  __shared__ int shPred;
  const int bid = blockIdx.x;
  const int tid = threadIdx.x;
  const int wv = tid >> 6;
  const int l = tid & 63;

  if (bid < 32) {
    // ========================= obj role (16 dims) ==========================
    const int q = l >> 2, qt = l & 3, dq = q >> 2, gq = q & 3;
    const int d0w = bid * 16 + wv * 4;
    const int colw = gq * HID + d0w + dq;
    {
      const float* base = objWh + (size_t)(qt * 128) * G4 + colw;
#pragma unroll 4
      for (int j4 = 0; j4 < 32; ++j4) {
        float4 t;
        t.x = base[(size_t)(4 * j4 + 0) * G4];
        t.y = base[(size_t)(4 * j4 + 1) * G4];
        t.z = base[(size_t)(4 * j4 + 2) * G4];
        t.w = base[(size_t)(4 * j4 + 3) * G4];
        w4[wv][j4][l] = t;
      }
    }
    for (int i = tid; i < 532; i += 256) hl[i] = 0.f;
    __syncthreads();

    float creg = 0.f;
    bool dead = false;
    for (int s = 0; s < TSTEPS; ++s) {
      float pre_v = preO[(size_t)s * G4 + colw];
      if (s > 0) {
        if (wv == 0) {
          const ull* src = encX + (size_t)(s - 1) * HID + l * 8;
          ull pv[8];
          if (!dead) {
            int tries = 0;
            for (;;) {
              unsigned tmin = 0xFFFFFFFFu;
#pragma unroll
              for (int j = 0; j < 8; ++j) {
                pv[j] = __hip_atomic_load(src + j, __ATOMIC_RELAXED, __HIP_MEMORY_SCOPE_AGENT);
                tmin = min(tmin, (unsigned)(pv[j] >> 32));
              }
              if (__all((int)(tmin >= (unsigned)s))) break;
              if (++tries > SPIN_FUSED) { dead = true; break; }
              __builtin_amdgcn_s_sleep(2);
            }
          }
          if (dead) {
#pragma unroll
            for (int j = 0; j < 8; ++j) pv[j] = 0ull;
          }
          const int pp = 8 * l + 4 * (l >> 4);
#pragma unroll
          for (int j = 0; j < 8; ++j) hl[pp + j] = __uint_as_float((unsigned)pv[j]);
        }
        __syncthreads();
      }
      float a0 = 0.f, a1 = 0.f, a2 = 0.f, a3 = 0.f;
      const float* hseg = &hl[132 * qt];
#pragma unroll
      for (int j4 = 0; j4 < 32; ++j4) {
        float4 w = w4[wv][j4][l];
        float4 h4 = *reinterpret_cast<const float4*>(&hseg[4 * j4]);
        a0 = fmaf(w.x, h4.x, a0); a1 = fmaf(w.y, h4.y, a1);
        a2 = fmaf(w.z, h4.z, a2); a3 = fmaf(w.w, h4.w, a3);
      }
      float acc = (a0 + a1) + (a2 + a3);
      acc += __shfl_xor(acc, 1);
      acc += __shfl_xor(acc, 2);
      float full = acc + pre_v;
      int gbase = (l & 48) | (l & 3);
      float vi = __shfl(full, gbase), vf = __shfl(full, gbase | 4);
      float vg = __shfl(full, gbase | 8), vo = __shfl(full, gbase | 12);
      float si = 1.f / (1.f + __expf(-vi));
      float sf = 1.f / (1.f + __expf(-vf));
      float so = 1.f / (1.f + __expf(-vo));
      creg = sf * creg + si * tanhf(vg);
      float h = so * tanhf(creg);
      if ((l & 15) == 0) {
        int dim = d0w + (l >> 4);
        ull pvs = ((ull)(unsigned)(s + 1) << 32) | (unsigned)__float_as_uint(h);
        __hip_atomic_store(encX + (size_t)s * HID + dim, pvs, __ATOMIC_RELAXED,
                           __HIP_MEMORY_SCOPE_AGENT);
      }
    }
  } else if (bid < 96) {
    // ========================= dec role (8 dims) ===========================
    rec8_body(bid - 32, preD, decWh, decWi2, dechX, encX,
              nullptr, nullptr, nullptr, w4, hl, &shPred);
  } else if (bid < 112) {
    // ===================== argmax role (rows a, a+16, ...) =================
    const int a = bid - 96;
    float* dh = hl;            // [0,512)
    float* lg = hl + 512;      // [512,663)
    bool dead = false;
    for (int r = a; r < TSTEPS; r += 16) {
      if (wv == 0) {
        const ull* src = dechX + (size_t)r * HID + l * 8;
        ull pv[8];
        if (!dead) {
          int tries = 0;
          for (;;) {
            unsigned tmin = 0xFFFFFFFFu;
#pragma unroll
            for (int j = 0; j < 8; ++j) {
              pv[j] = __hip_atomic_load(src + j, __ATOMIC_RELAXED, __HIP_MEMORY_SCOPE_AGENT);
              tmin = min(tmin, (unsigned)(pv[j] >> 32));
            }
            if (__all((int)(tmin >= (unsigned)(r + 1)))) break;
            if (++tries > SPIN_FUSED) { dead = true; break; }
            __builtin_amdgcn_s_sleep(2);
          }
        }
        if (dead) {
#pragma unroll
          for (int j = 0; j < 8; ++j) pv[j] = 0ull;
        }
#pragma unroll
        for (int j = 0; j < 8; ++j) dh[l * 8 + j] = __uint_as_float((unsigned)pv[j]);
      }
      __syncthreads();
      if (tid < NUM_CLASSES) {
        float s2 = outB[tid];
#pragma unroll 8
        for (int k = 0; k < HID; ++k)
          s2 = fmaf(dh[k], outW[(size_t)k * NUM_CLASSES + tid], s2);
        lg[tid] = s2;
        out[(size_t)r * NUM_CLASSES + tid] = s2;
      }
      __syncthreads();
      if (wv == 0) {
        float bv = -3.4e38f;
        int bi = NUM_CLASSES;
        for (int cc = l; cc < NUM_CLASSES; cc += 64) {
          float v = lg[cc];
          if (v > bv) { bv = v; bi = cc; }
        }
        for (int off = 32; off; off >>= 1) {
          float ov = __shfl_xor(bv, off);
          int oi = __shfl_xor(bi, off);
          if (ov > bv || (ov == bv && oi < bi)) { bv = ov; bi = oi; }
        }
        if (l == 0) {
          out[OUT_PRED + r] = (float)bi;
          ull pvs = ((ull)(unsigned)(r + 1) << 32) | (unsigned)bi;
          __hip_atomic_store(predX + r, pvs, __ATOMIC_RELAXED, __HIP_MEMORY_SCOPE_AGENT);
        }
      }
      __syncthreads();
    }
  } else {
    // ========================= edge role (8 dims) ==========================
    rec8_body(bid - 112, epre, edgeWh, edgeWi2, edgeX, encX,
              predX, embT, out + OUT_EDGE, w4, hl, &shPred);
  }
}

// ----------------------------------------------------------------------------
extern "C" void kernel_launch(void* const* d_in, const int* in_sizes, int n_in,
                              void* d_out, int out_size, void* d_ws, size_t ws_size,
                              hipStream_t stream) {
  const float* x        = (const float*)d_in[0];
  const float* odists   = (const float*)d_in[1];
  const float* box      = (const float*)d_in[2];
  const float* embed1   = (const float*)d_in[5];
  const float* embed2   = (const float*)d_in[6];
  const float* pos_W1   = (const float*)d_in[7];
  const float* pos_b1   = (const float*)d_in[8];
  const float* bn_gamma = (const float*)d_in[9];
  const float* bn_beta  = (const float*)d_in[10];
  const float* bn_mean  = (const float*)d_in[11];
  const float* bn_var   = (const float*)d_in[12];
  const float* pos_W2   = (const float*)d_in[13];
  const float* pos_b2   = (const float*)d_in[14];
  const float* obj_Wi   = (const float*)d_in[15];
  const float* obj_Wh   = (const float*)d_in[16];
  const float* obj_b    = (const float*)d_in[17];
  const float* dec_Wi   = (const float*)d_in[18];
  const float* dec_Wh   = (const float*)d_in[19];
  const float* dec_b    = (const float*)d_in[20];
  const float* out_W    = (const float*)d_in[21];
  const float* out_b    = (const float*)d_in[22];
  const float* edge_Wi  = (const float*)d_in[23];
  const float* edge_Wh  = (const float*)d_in[24];
  const float* edge_b   = (const float*)d_in[25];

  float* out = (float*)d_out;

  // workspace layout (79.4 MB; R12's executed overlap branch proved ws>=82.5MB)
  float* preO   = (float*)d_ws;                        // 2048x2048
  float* preD   = preO + (size_t)TSTEPS * G4;          // 2048x2048
  float* epre   = preD + (size_t)TSTEPS * G4;          // 2048x2048
  float* objemb = epre + (size_t)TSTEPS * G4;          // 2048x200
  float* posemb = objemb + (size_t)TSTEPS * EMBED;     // 2048x128
  float* embT   = posemb + (size_t)TSTEPS * POS;       // 151x2048
  ull* encX  = (ull*)(embT + (size_t)NUM_CLASSES * G4);// 2048x512 tagged
  ull* dechX = encX + (size_t)TSTEPS * HID;            // 2048x512 tagged
  ull* edgeX = dechX + (size_t)TSTEPS * HID;           // 2048x512 tagged
  ull* predX = edgeX + (size_t)TSTEPS * HID;           // 2048 tagged

  const size_t need_bytes =
      ((size_t)3 * TSTEPS * G4 + (size_t)TSTEPS * (EMBED + POS) +
       (size_t)NUM_CLASSES * G4) * 4 +
      ((size_t)3 * TSTEPS * HID + TSTEPS) * 8 + 256;
  if (ws_size < need_bytes) return;  // fail loudly, don't corrupt

  // 1) small embeds (compact)
  obj_embed2_kernel<<<TSTEPS, 256, 0, stream>>>(odists, embed1, objemb);
  pos2_kernel<<<TSTEPS, 128, 0, stream>>>(box, pos_W1, pos_b1, bn_gamma, bn_beta, bn_mean,
                                          bn_var, pos_W2, pos_b2, posemb);

  // 2) zero all tagged exchanges (poison-safe; required every launch)
  init_sync_kernel<<<2048, 256, 0, stream>>>((unsigned*)encX,
                                             ((long)3 * TSTEPS * HID + TSTEPS) * 2);

  // 3) pre-activation GEMMs, K-decomposed (no feats materialization)
  gemm48_kernel<0><<<dim3(16, 32), 256, 0, stream>>>(x, OBJ_DIM, obj_Wi, G4, obj_b,
                                                     preO, G4, TSTEPS, G4, OBJ_DIM);
  gemm_kernel<1><<<dim3(32, 32), 256, 0, stream>>>(objemb, EMBED, obj_Wi + (size_t)4096 * G4,
                                                   G4, nullptr, preO, G4, TSTEPS, G4, EMBED);
  gemm_kernel<1><<<dim3(32, 32), 256, 0, stream>>>(posemb, POS, obj_Wi + (size_t)4296 * G4,
                                                   G4, nullptr, preO, G4, TSTEPS, G4, POS);
  gemm48_kernel<0><<<dim3(16, 32), 256, 0, stream>>>(x, OBJ_DIM, dec_Wi, G4, dec_b,
                                                     preD, G4, TSTEPS, G4, OBJ_DIM);
  gemm_kernel<1><<<dim3(32, 32), 256, 0, stream>>>(objemb, EMBED, dec_Wi + (size_t)4096 * G4,
                                                   G4, nullptr, preD, G4, TSTEPS, G4, EMBED);
  gemm_kernel<1><<<dim3(32, 32), 256, 0, stream>>>(posemb, POS, dec_Wi + (size_t)4296 * G4,
                                                   G4, nullptr, preD, G4, TSTEPS, G4, POS);
  gemm48_kernel<0><<<dim3(16, 32), 256, 0, stream>>>(x, OBJ_DIM, edge_Wi + (size_t)200 * G4,
                                                     G4, edge_b, epre, G4, TSTEPS, G4, OBJ_DIM);
  gemm_kernel<0><<<dim3(32, 3), 256, 0, stream>>>(embed2, EMBED, edge_Wi, G4, nullptr,
                                                  embT, G4, NUM_CLASSES, G4, EMBED);

  // 4) the mega-fused pipeline: all three scans + logits + argmax + outputs
  fused_all_kernel<<<176, 256, 0, stream>>>(preO, obj_Wh, preD, dec_Wh,
                                            dec_Wi + (size_t)OBJ_IN * G4,
                                            epre, embT, edge_Wh,
                                            edge_Wi + (size_t)4296 * G4,
                                            out_W, out_b,
                                            encX, dechX, edgeX, predX, out);
}

// Round 20
// 9934.681 us; speedup vs baseline: 1.2151x; 1.2151x over previous
//
#include <hip/hip_runtime.h>
#include <cstdint>
#include <cstddef>

#define N_OBJ 2048
#define NUM_CLASSES 151
#define EMBED 200
#define HID 512
#define OBJ_DIM 4096
#define POS 128
#define OBJ_IN 4424   // 4096+200+128
#define EDGE_IN 4808  // 200+4096+512
#define G4 2048       // 4*HID
#define TSTEPS 2048   // virtual rows are causally dead (outputs sliced [:2048])
#define SPIN_FUSED 12000
#define OUT_PRED 309248
#define OUT_EDGE 311296

typedef unsigned long long ull;

// ----------------------------------------------------------------------------
// utility kernels
// ----------------------------------------------------------------------------
__global__ void init_sync_kernel(unsigned* p, long n) {
  long i = blockIdx.x * (long)blockDim.x + threadIdx.x;
  long stride = (long)gridDim.x * blockDim.x;
  for (; i < n; i += stride) p[i] = 0u;
}

// objemb[r][0:200] = obj_dists_in[r] @ embed1  (compact, ld=200)
__global__ void obj_embed2_kernel(const float* __restrict__ dists,
                                  const float* __restrict__ embed1,
                                  float* __restrict__ objemb) {
  int r = blockIdx.x;
  __shared__ float drow[NUM_CLASSES];
  for (int c = threadIdx.x; c < NUM_CLASSES; c += blockDim.x)
    drow[c] = dists[(size_t)r * NUM_CLASSES + c];
  __syncthreads();
  for (int j = threadIdx.x; j < EMBED; j += blockDim.x) {
    float s = 0.f;
    for (int k = 0; k < NUM_CLASSES; ++k)
      s = fmaf(drow[k], embed1[(size_t)k * EMBED + j], s);
    objemb[(size_t)r * EMBED + j] = s;
  }
}

// posemb[r][0:128] = relu(BN(box@W1+b1)@W2+b2)  (compact, ld=128)
__global__ void pos2_kernel(const float* __restrict__ box,
                            const float* __restrict__ W1, const float* __restrict__ b1,
                            const float* __restrict__ gamma, const float* __restrict__ beta,
                            const float* __restrict__ mean, const float* __restrict__ var,
                            const float* __restrict__ W2, const float* __restrict__ b2,
                            float* __restrict__ posemb) {
  int r = blockIdx.x;
  __shared__ float h[32];
  __shared__ float bx[9];
  if (threadIdx.x < 9) bx[threadIdx.x] = box[(size_t)r * 9 + threadIdx.x];
  __syncthreads();
  if (threadIdx.x < 32) {
    float s = b1[threadIdx.x];
    for (int k = 0; k < 9; ++k) s = fmaf(bx[k], W1[k * 32 + threadIdx.x], s);
    s = (s - mean[threadIdx.x]) * (1.f / sqrtf(var[threadIdx.x] + 1e-5f)) * gamma[threadIdx.x]
        + beta[threadIdx.x];
    h[threadIdx.x] = s;
  }
  __syncthreads();
  int j = threadIdx.x;
  if (j < POS) {
    float s = b2[j];
    for (int k = 0; k < 32; ++k) s = fmaf(h[k], W2[k * POS + j], s);
    posemb[(size_t)r * POS + j] = fmaxf(s, 0.f);
  }
}

// ----------------------------------------------------------------------------
// 64x64 GEMM (R11-proven): C = A@B (+bias if !ACC, += if ACC), bounds-checked
// ----------------------------------------------------------------------------
template <int ACC>
__global__ __launch_bounds__(256)
void gemm_kernel(const float* __restrict__ A, int lda,
                 const float* __restrict__ B, int ldb,
                 const float* __restrict__ bias,
                 float* __restrict__ C, int ldc,
                 int M, int N, int K) {
  __shared__ __align__(16) float As[16][68];
  __shared__ __align__(16) float Bs[16][64];
  const int row0 = blockIdx.y * 64;
  const int col0 = blockIdx.x * 64;
  const int tid = threadIdx.x;
  const int tx = tid & 15, ty = tid >> 4;
  float acc[4][4] = {};

  for (int k0 = 0; k0 < K; k0 += 16) {
#pragma unroll
    for (int l = 0; l < 4; ++l) {
      int idx = tid + l * 256;
      int m = idx >> 4, kk = idx & 15;
      int gm = row0 + m, gk = k0 + kk;
      As[kk][m] = (gm < M && gk < K) ? A[(size_t)gm * lda + gk] : 0.f;
    }
#pragma unroll
    for (int l = 0; l < 4; ++l) {
      int idx = tid + l * 256;
      int kk = idx >> 6, n = idx & 63;
      int gk = k0 + kk, gn = col0 + n;
      Bs[kk][n] = (gk < K && gn < N) ? B[(size_t)gk * ldb + gn] : 0.f;
    }
    __syncthreads();
#pragma unroll
    for (int kk = 0; kk < 16; ++kk) {
      float4 a = *reinterpret_cast<const float4*>(&As[kk][ty * 4]);
      float4 b = *reinterpret_cast<const float4*>(&Bs[kk][tx * 4]);
      acc[0][0] = fmaf(a.x, b.x, acc[0][0]); acc[0][1] = fmaf(a.x, b.y, acc[0][1]);
      acc[0][2] = fmaf(a.x, b.z, acc[0][2]); acc[0][3] = fmaf(a.x, b.w, acc[0][3]);
      acc[1][0] = fmaf(a.y, b.x, acc[1][0]); acc[1][1] = fmaf(a.y, b.y, acc[1][1]);
      acc[1][2] = fmaf(a.y, b.z, acc[1][2]); acc[1][3] = fmaf(a.y, b.w, acc[1][3]);
      acc[2][0] = fmaf(a.z, b.x, acc[2][0]); acc[2][1] = fmaf(a.z, b.y, acc[2][1]);
      acc[2][2] = fmaf(a.z, b.z, acc[2][2]); acc[2][3] = fmaf(a.z, b.w, acc[2][3]);
      acc[3][0] = fmaf(a.w, b.x, acc[3][0]); acc[3][1] = fmaf(a.w, b.y, acc[3][1]);
      acc[3][2] = fmaf(a.w, b.z, acc[3][2]); acc[3][3] = fmaf(a.w, b.w, acc[3][3]);
    }
    __syncthreads();
  }
#pragma unroll
  for (int i = 0; i < 4; ++i) {
    int gm = row0 + ty * 4 + i;
    if (gm >= M) continue;
#pragma unroll
    for (int j = 0; j < 4; ++j) {
      int gn = col0 + tx * 4 + j;
      if (gn >= N) continue;
      size_t o = (size_t)gm * ldc + gn;
      if (ACC) C[o] += acc[i][j];
      else C[o] = acc[i][j] + (bias ? bias[gn] : 0.f);
    }
  }
}

// ----------------------------------------------------------------------------
// MEGA-FUSED pipeline: obj scan -> dec scan -> argmax -> edge scan, one
// dispatch, 176 blocks (obj[0,32) 16 dims; dec[32,96) 8 dims; argmax[96,112);
// edge[112,176) 8 dims). Exchange: full-array tagged pairs {tag=s+1, payload}
// (encX/dechX/edgeX per (step,dim) slot; predX per step), relaxed/agent
// atomics (only proven-safe codegen), zero-init per launch (poison-safe),
// no ring/lap hazards, no backpressure. Bounded spins + sticky dead-latch:
// worst case loud absmax fail, never a hang. Scan blocks: 135KB LDS -> 1/CU.
// R16 lesson: keep the COMBINED poll (overlapped loads, one RTT) — split
// polls serialize into 3 dependent RTTs and regress 15%.
// ----------------------------------------------------------------------------
__device__ __forceinline__ void rec8_body(
    int blk, const float* __restrict__ pre, const float* __restrict__ Wh,
    const float* __restrict__ Wi2, ull* hXown, const ull* encXc,
    const ull* predX, const float* __restrict__ embT, float* outEdge,
    float4 (*w4)[32][64], float* hl, int* shPred) {
  const int tid = threadIdx.x;
  const int wv = tid >> 6;
  const int l = tid & 63;
  const int o = l & 7;          // k-octant (128 k each; o<4 = own-h, o>=4 = enc)
  const int c = l >> 3;         // col-in-wave 0..7
  const int gq = c & 3;         // gate
  const int dl = c >> 2;        // dim-in-wave 0..1
  const int dim = blk * 8 + 2 * wv + dl;
  const int colw = gq * HID + dim;
  {
    const float* srcW = (o < 4) ? (Wh + (size_t)(o * 128) * G4 + colw)
                                : (Wi2 + (size_t)((o - 4) * 128) * G4 + colw);
#pragma unroll 4
    for (int j4 = 0; j4 < 32; ++j4) {
      float4 t;
      t.x = srcW[(size_t)(4 * j4 + 0) * G4];
      t.y = srcW[(size_t)(4 * j4 + 1) * G4];
      t.z = srcW[(size_t)(4 * j4 + 2) * G4];
      t.w = srcW[(size_t)(4 * j4 + 3) * G4];
      w4[wv][j4][l] = t;
    }
  }
  for (int i = tid; i < 1056; i += 256) hl[i] = 0.f;
  __syncthreads();

  float creg = 0.f;
  bool dead = false;
  for (int s = 0; s < TSTEPS; ++s) {
    float pre_v = pre[(size_t)s * G4 + colw];
    if (wv == 0) {
      const ull* srcE = encXc + (size_t)s * HID + l * 8;
      const ull* srcH = hXown + (size_t)(s - 1) * HID + l * 8;  // deref iff s>0
      ull pe[8], ph[8], pp = 0;
      if (!dead) {
        int tries = 0;
        for (;;) {
          unsigned tE = 0xFFFFFFFFu, tH = 0xFFFFFFFFu, tP = 0xFFFFFFFFu;
#pragma unroll
          for (int j = 0; j < 8; ++j) {
            pe[j] = __hip_atomic_load(srcE + j, __ATOMIC_RELAXED, __HIP_MEMORY_SCOPE_AGENT);
            tE = min(tE, (unsigned)(pe[j] >> 32));
          }
          if (s > 0) {
#pragma unroll
            for (int j = 0; j < 8; ++j) {
              ph[j] = __hip_atomic_load(srcH + j, __ATOMIC_RELAXED, __HIP_MEMORY_SCOPE_AGENT);
              tH = min(tH, (unsigned)(ph[j] >> 32));
            }
          }
          if (predX) {
            pp = __hip_atomic_load(predX + s, __ATOMIC_RELAXED, __HIP_MEMORY_SCOPE_AGENT);
            tP = (unsigned)(pp >> 32);
          }
          bool ok = (tE >= (unsigned)(s + 1)) && (s == 0 || tH >= (unsigned)s) &&
                    (!predX || tP >= (unsigned)(s + 1));
          if (__all((int)ok)) break;
          if (++tries > SPIN_FUSED) { dead = true; break; }
          __builtin_amdgcn_s_sleep(2);
        }
      }
      if (dead) {
#pragma unroll
        for (int j = 0; j < 8; ++j) { pe[j] = 0ull; ph[j] = 0ull; }
        pp = 0;
      }
      const int ppH = 8 * l + 4 * (l >> 4);
      const int ppE = 528 + ppH;
      if (s > 0) {
#pragma unroll
        for (int j = 0; j < 8; ++j) hl[ppH + j] = __uint_as_float((unsigned)ph[j]);
      }
#pragma unroll
      for (int j = 0; j < 8; ++j) hl[ppE + j] = __uint_as_float((unsigned)pe[j]);
      if (predX && l == 0) *shPred = (int)(unsigned)(pp & 0xFFFFFFFFull);
    }
    __syncthreads();

    float emb = 0.f;
    if (embT) emb = embT[(size_t)(*shPred) * G4 + colw];

    float a0 = 0.f, a1 = 0.f, a2 = 0.f, a3 = 0.f;
    const float* hseg = &hl[132 * o];
#pragma unroll
    for (int j4 = 0; j4 < 32; ++j4) {
      float4 w = w4[wv][j4][l];
      float4 h4 = *reinterpret_cast<const float4*>(&hseg[4 * j4]);
      a0 = fmaf(w.x, h4.x, a0); a1 = fmaf(w.y, h4.y, a1);
      a2 = fmaf(w.z, h4.z, a2); a3 = fmaf(w.w, h4.w, a3);
    }
    float acc = (a0 + a1) + (a2 + a3);
    acc += __shfl_xor(acc, 1);
    acc += __shfl_xor(acc, 2);
    acc += __shfl_xor(acc, 4);
    float full = acc + pre_v + emb;
    int gb = dl * 32;  // lanes gb, gb+8, gb+16, gb+24 hold gates i,f,g,o (R14/R15-verified)
    float vi = __shfl(full, gb), vf = __shfl(full, gb + 8);
    float vg = __shfl(full, gb + 16), vo = __shfl(full, gb + 24);
    float si = 1.f / (1.f + __expf(-vi));
    float sf = 1.f / (1.f + __expf(-vf));
    float so = 1.f / (1.f + __expf(-vo));
    creg = sf * creg + si * tanhf(vg);
    float h = so * tanhf(creg);
    if ((l & 31) == 0) {
      if (outEdge) outEdge[(size_t)s * HID + dim] = h;
      ull pvs = ((ull)(unsigned)(s + 1) << 32) | (unsigned)__float_as_uint(h);
      __hip_atomic_store(hXown + (size_t)s * HID + dim, pvs, __ATOMIC_RELAXED,
                         __HIP_MEMORY_SCOPE_AGENT);
    }
  }
}

__global__ __launch_bounds__(256, 1)
void fused_all_kernel(const float* __restrict__ preO, const float* __restrict__ objWh,
                      const float* __restrict__ preD, const float* __restrict__ decWh,
                      const float* __restrict__ decWi2,
                      const float* __restrict__ epre, const float* __restrict__ embT,
                      const float* __restrict__ edgeWh, const float* __restrict__ edgeWi2,
                      const float* __restrict__ outW, const float* __restrict__ outB,
                      ull* encX, ull* dechX, ull* edgeX, ull* predX,
                      float* out) {
  __shared__ float4 w4[4][32][64];   // 128 KB
  __shared__ float hl[1056];         // scan h staging / argmax dh+logits
  __shared__ int shPred;
  const int bid = blockIdx.x;
  const int tid = threadIdx.x;
  const int wv = tid >> 6;
  const int l = tid & 63;

  if (bid < 32) {
    // ========================= obj role (16 dims) ==========================
    const int q = l >> 2, qt = l & 3, dq = q >> 2, gq = q & 3;
    const int d0w = bid * 16 + wv * 4;
    const int colw = gq * HID + d0w + dq;
    {
      const float* base = objWh + (size_t)(qt * 128) * G4 + colw;
#pragma unroll 4
      for (int j4 = 0; j4 < 32; ++j4) {
        float4 t;
        t.x = base[(size_t)(4 * j4 + 0) * G4];
        t.y = base[(size_t)(4 * j4 + 1) * G4];
        t.z = base[(size_t)(4 * j4 + 2) * G4];
        t.w = base[(size_t)(4 * j4 + 3) * G4];
        w4[wv][j4][l] = t;
      }
    }
    for (int i = tid; i < 532; i += 256) hl[i] = 0.f;
    __syncthreads();

    float creg = 0.f;
    bool dead = false;
    for (int s = 0; s < TSTEPS; ++s) {
      float pre_v = preO[(size_t)s * G4 + colw];
      if (s > 0) {
        if (wv == 0) {
          const ull* src = encX + (size_t)(s - 1) * HID + l * 8;
          ull pv[8];
          if (!dead) {
            int tries = 0;
            for (;;) {
              unsigned tmin = 0xFFFFFFFFu;
#pragma unroll
              for (int j = 0; j < 8; ++j) {
                pv[j] = __hip_atomic_load(src + j, __ATOMIC_RELAXED, __HIP_MEMORY_SCOPE_AGENT);
                tmin = min(tmin, (unsigned)(pv[j] >> 32));
              }
              if (__all((int)(tmin >= (unsigned)s))) break;
              if (++tries > SPIN_FUSED) { dead = true; break; }
              __builtin_amdgcn_s_sleep(2);
            }
          }
          if (dead) {
#pragma unroll
            for (int j = 0; j < 8; ++j) pv[j] = 0ull;
          }
          const int pp = 8 * l + 4 * (l >> 4);
#pragma unroll
          for (int j = 0; j < 8; ++j) hl[pp + j] = __uint_as_float((unsigned)pv[j]);
        }
        __syncthreads();
      }
      float a0 = 0.f, a1 = 0.f, a2 = 0.f, a3 = 0.f;
      const float* hseg = &hl[132 * qt];
#pragma unroll
      for (int j4 = 0; j4 < 32; ++j4) {
        float4 w = w4[wv][j4][l];
        float4 h4 = *reinterpret_cast<const float4*>(&hseg[4 * j4]);
        a0 = fmaf(w.x, h4.x, a0); a1 = fmaf(w.y, h4.y, a1);
        a2 = fmaf(w.z, h4.z, a2); a3 = fmaf(w.w, h4.w, a3);
      }
      float acc = (a0 + a1) + (a2 + a3);
      acc += __shfl_xor(acc, 1);
      acc += __shfl_xor(acc, 2);
      float full = acc + pre_v;
      int gbase = (l & 48) | (l & 3);
      float vi = __shfl(full, gbase), vf = __shfl(full, gbase | 4);
      float vg = __shfl(full, gbase | 8), vo = __shfl(full, gbase | 12);
      float si = 1.f / (1.f + __expf(-vi));
      float sf = 1.f / (1.f + __expf(-vf));
      float so = 1.f / (1.f + __expf(-vo));
      creg = sf * creg + si * tanhf(vg);
      float h = so * tanhf(creg);
      if ((l & 15) == 0) {
        int dim = d0w + (l >> 4);
        ull pvs = ((ull)(unsigned)(s + 1) << 32) | (unsigned)__float_as_uint(h);
        __hip_atomic_store(encX + (size_t)s * HID + dim, pvs, __ATOMIC_RELAXED,
                           __HIP_MEMORY_SCOPE_AGENT);
      }
    }
  } else if (bid < 96) {
    // ========================= dec role (8 dims) ===========================
    rec8_body(bid - 32, preD, decWh, decWi2, dechX, encX,
              nullptr, nullptr, nullptr, w4, hl, &shPred);
  } else if (bid < 112) {
    // ===================== argmax role (rows a, a+16, ...) =================
    const int a = bid - 96;
    float* dh = hl;            // [0,512)
    float* lg = hl + 512;      // [512,663)
    bool dead = false;
    for (int r = a; r < TSTEPS; r += 16) {
      if (wv == 0) {
        const ull* src = dechX + (size_t)r * HID + l * 8;
        ull pv[8];
        if (!dead) {
          int tries = 0;
          for (;;) {
            unsigned tmin = 0xFFFFFFFFu;
#pragma unroll
            for (int j = 0; j < 8; ++j) {
              pv[j] = __hip_atomic_load(src + j, __ATOMIC_RELAXED, __HIP_MEMORY_SCOPE_AGENT);
              tmin = min(tmin, (unsigned)(pv[j] >> 32));
            }
            if (__all((int)(tmin >= (unsigned)(r + 1)))) break;
            if (++tries > SPIN_FUSED) { dead = true; break; }
            __builtin_amdgcn_s_sleep(2);
          }
        }
        if (dead) {
#pragma unroll
          for (int j = 0; j < 8; ++j) pv[j] = 0ull;
        }
#pragma unroll
        for (int j = 0; j < 8; ++j) dh[l * 8 + j] = __uint_as_float((unsigned)pv[j]);
      }
      __syncthreads();
      if (tid < NUM_CLASSES) {
        float s2 = outB[tid];
#pragma unroll 8
        for (int k = 0; k < HID; ++k)
          s2 = fmaf(dh[k], outW[(size_t)k * NUM_CLASSES + tid], s2);
        lg[tid] = s2;
        out[(size_t)r * NUM_CLASSES + tid] = s2;
      }
      __syncthreads();
      if (wv == 0) {
        float bv = -3.4e38f;
        int bi = NUM_CLASSES;
        for (int cc = l; cc < NUM_CLASSES; cc += 64) {
          float v = lg[cc];
          if (v > bv) { bv = v; bi = cc; }
        }
        for (int off = 32; off; off >>= 1) {
          float ov = __shfl_xor(bv, off);
          int oi = __shfl_xor(bi, off);
          if (ov > bv || (ov == bv && oi < bi)) { bv = ov; bi = oi; }
        }
        if (l == 0) {
          out[OUT_PRED + r] = (float)bi;
          ull pvs = ((ull)(unsigned)(r + 1) << 32) | (unsigned)bi;
          __hip_atomic_store(predX + r, pvs, __ATOMIC_RELAXED, __HIP_MEMORY_SCOPE_AGENT);
        }
      }
      __syncthreads();
    }
  } else {
    // ========================= edge role (8 dims) ==========================
    rec8_body(bid - 112, epre, edgeWh, edgeWi2, edgeX, encX,
              predX, embT, out + OUT_EDGE, w4, hl, &shPred);
  }
}

// ----------------------------------------------------------------------------
extern "C" void kernel_launch(void* const* d_in, const int* in_sizes, int n_in,
                              void* d_out, int out_size, void* d_ws, size_t ws_size,
                              hipStream_t stream) {
  const float* x        = (const float*)d_in[0];
  const float* odists   = (const float*)d_in[1];
  const float* box      = (const float*)d_in[2];
  const float* embed1   = (const float*)d_in[5];
  const float* embed2   = (const float*)d_in[6];
  const float* pos_W1   = (const float*)d_in[7];
  const float* pos_b1   = (const float*)d_in[8];
  const float* bn_gamma = (const float*)d_in[9];
  const float* bn_beta  = (const float*)d_in[10];
  const float* bn_mean  = (const float*)d_in[11];
  const float* bn_var   = (const float*)d_in[12];
  const float* pos_W2   = (const float*)d_in[13];
  const float* pos_b2   = (const float*)d_in[14];
  const float* obj_Wi   = (const float*)d_in[15];
  const float* obj_Wh   = (const float*)d_in[16];
  const float* obj_b    = (const float*)d_in[17];
  const float* dec_Wi   = (const float*)d_in[18];
  const float* dec_Wh   = (const float*)d_in[19];
  const float* dec_b    = (const float*)d_in[20];
  const float* out_W    = (const float*)d_in[21];
  const float* out_b    = (const float*)d_in[22];
  const float* edge_Wi  = (const float*)d_in[23];
  const float* edge_Wh  = (const float*)d_in[24];
  const float* edge_b   = (const float*)d_in[25];

  float* out = (float*)d_out;

  // workspace layout (79.4 MB; R12's executed overlap branch proved ws>=82.5MB)
  float* preO   = (float*)d_ws;                        // 2048x2048
  float* preD   = preO + (size_t)TSTEPS * G4;          // 2048x2048
  float* epre   = preD + (size_t)TSTEPS * G4;          // 2048x2048
  float* objemb = epre + (size_t)TSTEPS * G4;          // 2048x200
  float* posemb = objemb + (size_t)TSTEPS * EMBED;     // 2048x128
  float* embT   = posemb + (size_t)TSTEPS * POS;       // 151x2048
  ull* encX  = (ull*)(embT + (size_t)NUM_CLASSES * G4);// 2048x512 tagged
  ull* dechX = encX + (size_t)TSTEPS * HID;            // 2048x512 tagged
  ull* edgeX = dechX + (size_t)TSTEPS * HID;           // 2048x512 tagged
  ull* predX = edgeX + (size_t)TSTEPS * HID;           // 2048 tagged

  const size_t need_bytes =
      ((size_t)3 * TSTEPS * G4 + (size_t)TSTEPS * (EMBED + POS) +
       (size_t)NUM_CLASSES * G4) * 4 +
      ((size_t)3 * TSTEPS * HID + TSTEPS) * 8 + 256;
  if (ws_size < need_bytes) return;  // fail loudly, don't corrupt

  // 1) small embeds (compact)
  obj_embed2_kernel<<<TSTEPS, 256, 0, stream>>>(odists, embed1, objemb);
  pos2_kernel<<<TSTEPS, 128, 0, stream>>>(box, pos_W1, pos_b1, bn_gamma, bn_beta, bn_mean,
                                          bn_var, pos_W2, pos_b2, posemb);

  // 2) zero all tagged exchanges (poison-safe; required every launch)
  init_sync_kernel<<<2048, 256, 0, stream>>>((unsigned*)encX,
                                             ((long)3 * TSTEPS * HID + TSTEPS) * 2);

  // 3) pre-activation GEMMs, K-decomposed (no feats materialization)
  gemm_kernel<0><<<dim3(32, 32), 256, 0, stream>>>(x, OBJ_DIM, obj_Wi, G4, obj_b,
                                                   preO, G4, TSTEPS, G4, OBJ_DIM);
  gemm_kernel<1><<<dim3(32, 32), 256, 0, stream>>>(objemb, EMBED, obj_Wi + (size_t)4096 * G4,
                                                   G4, nullptr, preO, G4, TSTEPS, G4, EMBED);
  gemm_kernel<1><<<dim3(32, 32), 256, 0, stream>>>(posemb, POS, obj_Wi + (size_t)4296 * G4,
                                                   G4, nullptr, preO, G4, TSTEPS, G4, POS);
  gemm_kernel<0><<<dim3(32, 32), 256, 0, stream>>>(x, OBJ_DIM, dec_Wi, G4, dec_b,
                                                   preD, G4, TSTEPS, G4, OBJ_DIM);
  gemm_kernel<1><<<dim3(32, 32), 256, 0, stream>>>(objemb, EMBED, dec_Wi + (size_t)4096 * G4,
                                                   G4, nullptr, preD, G4, TSTEPS, G4, EMBED);
  gemm_kernel<1><<<dim3(32, 32), 256, 0, stream>>>(posemb, POS, dec_Wi + (size_t)4296 * G4,
                                                   G4, nullptr, preD, G4, TSTEPS, G4, POS);
  gemm_kernel<0><<<dim3(32, 32), 256, 0, stream>>>(x, OBJ_DIM, edge_Wi + (size_t)200 * G4,
                                                   G4, edge_b, epre, G4, TSTEPS, G4, OBJ_DIM);
  gemm_kernel<0><<<dim3(32, 3), 256, 0, stream>>>(embed2, EMBED, edge_Wi, G4, nullptr,
                                                  embT, G4, NUM_CLASSES, G4, EMBED);

  // 4) the mega-fused pipeline: all three scans + logits + argmax + outputs
  fused_all_kernel<<<176, 256, 0, stream>>>(preO, obj_Wh, preD, dec_Wh,
                                            dec_Wi + (size_t)OBJ_IN * G4,
                                            epre, embT, edge_Wh,
                                            edge_Wi + (size_t)4296 * G4,
                                            out_W, out_b,
                                            encX, dechX, edgeX, predX, out);
}